// Round 7
// baseline (822.371 us; speedup 1.0000x reference)
//
#include <hip/hip_runtime.h>

// InteractionBlock: N=50000 nodes, M=32 nbrs, HID=128, FILT=128, NBR=64
//  k0 : node_repr f32 -> bf16 table in d_ws
//  k1 : per-node fused filter MLP (bf16 MFMA) + filter-weighted neighbor sum -> message (d_out)
//  k2a: u = silu(msg@uw1+ub1) -> bf16 u in d_ws (reuses k0 region)
//  k2b: out = u@uw2+ub2 -> d_out
//
// R6 -> R7 changes (diagnosis: FETCH is the cost function (dur = FETCH/2.95TB/s);
// 8B-lane gathers over-fetched 3.4x — per-instruction per-row footprint must be
// a full 128B line):
//  * gather = WAVE-COOPERATIVE half-row loads: 64 lanes x 2B = 128B = one line,
//    zero over-fetch by construction (R3-validated pattern), 64 instr/node
//  * filters bounce through a tiny per-wave bf16 LDS tile [16 m][64 hid + 4 pad]
//    written in 4 phases (hid-half x mt); m-sum is now IN-LANE (lane l owns
//    hid 64h+l) -> no DPP reduce, msg store fully coalesced
//  * nbr_idx via scalar s_loads (readfirstlane(n)) — one Kcache line per node
//  * LDS 70KB -> 2 blocks/CU; register pressure cut (no nr/pacc arrays)
//
// MFMA layout conventions (gfx950, 16x16 family, verified m89/m91):
//   A frag (16x16x32): row = lane&15, k = (lane>>4)*8 + j  (short8)
//   A/B frag (16x16x16bf16_1k): row/col = lane&15, k = (lane>>4)*4 + j (short4)
//   C/D: col = lane&15, row = (lane>>4)*4 + reg
// Transposed GEMM2 (A=w2 frag, B=P): lane holds filter[m=c][hid=16ct+4g+r].

#define NN 50000
#define MM 32
#define HID 128
#define NBR 64

typedef __attribute__((ext_vector_type(4))) float f32x4;
typedef __attribute__((ext_vector_type(8))) short s16x8;
typedef __attribute__((ext_vector_type(4))) short s16x4;

__device__ __forceinline__ short f2bf(float x) {
  unsigned u = __builtin_bit_cast(unsigned, x);
  unsigned r = (u + 0x7FFFu + ((u >> 16) & 1u)) >> 16;
  return (short)r;
}

__device__ __forceinline__ float bf2f(short b) {
  return __builtin_bit_cast(float, (unsigned)(unsigned short)b << 16);
}

__device__ __forceinline__ float silu(float x) {
  return x / (1.0f + __expf(-x));
}

// ---------------------------------------------------------------- kernel 0
__global__ __launch_bounds__(256) void k_cvt_node(
    const float* __restrict__ in, short* __restrict__ out)
{
  int i = blockIdx.x * 256 + threadIdx.x;            // float4 index
  if (i < NN * HID / 4) {
    f32x4 v = *(reinterpret_cast<const f32x4*>(in) + i);
    s16x4 o;
    #pragma unroll
    for (int r = 0; r < 4; ++r) o[r] = f2bf(v[r]);
    reinterpret_cast<s16x4*>(out)[i] = o;
  }
}

// ---------------------------------------------------------------- kernel 1
__global__ __launch_bounds__(512, 2) void k_filter_message(
    const short* __restrict__ node_bf, const float* __restrict__ nbr_fea,
    const int* __restrict__ nbr_idx, const float* __restrict__ fw1,
    const float* __restrict__ fb1, const float* __restrict__ fw2,
    const float* __restrict__ fb2, float* __restrict__ msg_out)
{
  __shared__ __align__(16) short s_w1[128 * 72];      // 18.0 KB  fw1T[f][k]
  __shared__ __align__(16) short s_w2[128 * 136];     // 34.0 KB  fw2T[h][k]
  __shared__ float s_b1[128];
  __shared__ __align__(16) float s_b2[128];
  __shared__ __align__(16) short s_ft[8][16 * 68];    // 17.0 KB  per-wave [m16][64hid+4pad]
  // total 70 KB -> 2 blocks/CU

  const int tid = threadIdx.x;
  for (int i = tid; i < 64 * 128; i += 512) {      // fw1 given [k<64][f<128]
    int k = i >> 7, f = i & 127;
    s_w1[f * 72 + k] = f2bf(fw1[i]);
  }
  for (int i = tid; i < 128 * 128; i += 512) {     // fw2 given [k<128][h<128]
    int k = i >> 7, h = i & 127;
    s_w2[h * 136 + k] = f2bf(fw2[i]);
  }
  if (tid < 128) { s_b1[tid] = fb1[tid]; s_b2[tid] = fb2[tid]; }
  __syncthreads();

  const int wave = tid >> 6, lane = tid & 63;
  const int c = lane & 15, g = lane >> 4;
  short* __restrict__ ft = s_ft[wave];             // wave-private, no barriers
  const int gw = blockIdx.x * 8 + wave;
  const int STRIDE = 512 * 8;   // 4096

  for (int n = gw; n < NN; n += STRIDE) {
    // scalar neighbor indices (wave-uniform n -> s_load, one Kcache line)
    const int sbase = __builtin_amdgcn_readfirstlane(n) * MM;
    int idxs[32];
    #pragma unroll
    for (int m = 0; m < 32; ++m) idxs[m] = nbr_idx[sbase + m];

    // stream nbr_fea (NT) -> B1 frags
    const float* nf = nbr_fea + (size_t)n * (MM * NBR);
    s16x8 b1[2][2];
    #pragma unroll
    for (int mt = 0; mt < 2; ++mt)
      #pragma unroll
      for (int kt = 0; kt < 2; ++kt) {
        const f32x4* src = reinterpret_cast<const f32x4*>(
            nf + (mt * 16 + c) * NBR + kt * 32 + g * 8);
        f32x4 lo = __builtin_nontemporal_load(src);
        f32x4 hi = __builtin_nontemporal_load(src + 1);
        s16x8 v;
        v[0] = f2bf(lo[0]); v[1] = f2bf(lo[1]); v[2] = f2bf(lo[2]); v[3] = f2bf(lo[3]);
        v[4] = f2bf(hi[0]); v[5] = f2bf(hi[1]); v[6] = f2bf(hi[2]); v[7] = f2bf(hi[3]);
        b1[mt][kt] = v;
      }

    // GEMM1 (transposed): h^T = fw1T . nbr^T  (16x16x32); bias+silu -> P frags
    s16x4 P[8][2];
    #pragma unroll
    for (int t = 0; t < 8; ++t) {
      f32x4 a0 = f32x4{0.f, 0.f, 0.f, 0.f};
      f32x4 a1 = f32x4{0.f, 0.f, 0.f, 0.f};
      #pragma unroll
      for (int kt = 0; kt < 2; ++kt) {
        s16x8 w1f = *reinterpret_cast<const s16x8*>(&s_w1[(t * 16 + c) * 72 + kt * 32 + g * 8]);
        a0 = __builtin_amdgcn_mfma_f32_16x16x32_bf16(w1f, b1[0][kt], a0, 0, 0, 0);
        a1 = __builtin_amdgcn_mfma_f32_16x16x32_bf16(w1f, b1[1][kt], a1, 0, 0, 0);
      }
      s16x4 p0, p1;
      #pragma unroll
      for (int r = 0; r < 4; ++r) {
        float bias = s_b1[t * 16 + g * 4 + r];
        p0[r] = f2bf(silu(a0[r] + bias));
        p1[r] = f2bf(silu(a1[r] + bias));
      }
      P[t][0] = p0;
      P[t][1] = p1;
    }

    // GEMM2 (transposed) + filter tile + cooperative gather-multiply,
    // 4 phases: (hid-half h) x (m-half mt). Lane l owns hid 64h+l in-lane.
    float msgA = 0.f, msgB = 0.f;    // hid = lane, hid = 64+lane
    #pragma unroll
    for (int h = 0; h < 2; ++h) {
      #pragma unroll
      for (int mt = 0; mt < 2; ++mt) {
        // compute filters for ct = 4h..4h+3, this mt; pack bf16 -> tile
        #pragma unroll
        for (int q = 0; q < 4; ++q) {
          const int ct = 4 * h + q;
          f32x4 t = f32x4{0.f, 0.f, 0.f, 0.f};
          #pragma unroll
          for (int kt = 0; kt < 8; ++kt) {
            s16x4 w2f = *reinterpret_cast<const s16x4*>(&s_w2[(ct * 16 + c) * 136 + kt * 16 + g * 4]);
            t = __builtin_amdgcn_mfma_f32_16x16x16bf16_1k(w2f, P[kt][mt], t, 0, 0, 0);
          }
          f32x4 fb = *reinterpret_cast<const f32x4*>(&s_b2[ct * 16 + 4 * g]);
          s16x4 pk;
          #pragma unroll
          for (int r = 0; r < 4; ++r) pk[r] = f2bf(t[r] + fb[r]);
          // lane holds f[m=c][hid=16ct+4g+r] -> tile[c][hid-in-half]
          *reinterpret_cast<s16x4*>(&ft[c * 68 + q * 16 + 4 * g]) = pk;
        }
        // cooperative gather: one 128B line per (m, half); in-lane FMA
        float a = 0.f;
        #pragma unroll
        for (int m = 0; m < 16; ++m) {
          const int idxm = idxs[mt * 16 + m];
          const short nv = node_bf[(size_t)idxm * HID + h * 64 + lane];
          const short fv = ft[m * 68 + lane];
          a += bf2f(fv) * bf2f(nv);
        }
        if (h == 0) msgA += a; else msgB += a;
      }
    }

    // coalesced message store (all 64 lanes)
    msg_out[(size_t)n * HID + lane] = msgA;
    msg_out[(size_t)n * HID + 64 + lane] = msgB;
  }
}

// ---------------------------------------------------------------- kernel 2a
// u^T = silu(uw1^T . msg^T + ub1) -> bf16 u[row][128] in ws
__global__ __launch_bounds__(256, 2) void k_update1(
    const float* __restrict__ msg, const float* __restrict__ uw1,
    const float* __restrict__ ub1, short* __restrict__ u_out)
{
  __shared__ __align__(16) short s_w1[128 * 136];   // uw1T[f][k], stride 136
  __shared__ float s_b1[128];
  const int tid = threadIdx.x;
  for (int i = tid; i < 128 * 128; i += 256) {      // uw1 given [k][f]
    int k = i >> 7, f = i & 127;
    s_w1[f * 136 + k] = f2bf(uw1[i]);
  }
  if (tid < 128) s_b1[tid] = ub1[tid];
  __syncthreads();

  const int wave = tid >> 6, lane = tid & 63;
  const int c = lane & 15, g = lane >> 4;
  const long base = (long)(blockIdx.x * 4 + wave) * 32;
  if (base >= NN) return;

  s16x8 bfr[2][4];
  #pragma unroll
  for (int mt = 0; mt < 2; ++mt)
    #pragma unroll
    for (int kt = 0; kt < 4; ++kt) {
      long row = base + mt * 16 + c; if (row > NN - 1) row = NN - 1;
      const float* src = msg + row * HID + kt * 32 + g * 8;
      float4 lo = *reinterpret_cast<const float4*>(src);
      float4 hi = *reinterpret_cast<const float4*>(src + 4);
      s16x8 v;
      v[0] = f2bf(lo.x); v[1] = f2bf(lo.y); v[2] = f2bf(lo.z); v[3] = f2bf(lo.w);
      v[4] = f2bf(hi.x); v[5] = f2bf(hi.y); v[6] = f2bf(hi.z); v[7] = f2bf(hi.w);
      bfr[mt][kt] = v;
    }

  f32x4 acc[8][2];
  #pragma unroll
  for (int t = 0; t < 8; ++t)
    #pragma unroll
    for (int mt = 0; mt < 2; ++mt)
      acc[t][mt] = f32x4{0.f, 0.f, 0.f, 0.f};
  #pragma unroll
  for (int kt = 0; kt < 4; ++kt)
    #pragma unroll
    for (int t = 0; t < 8; ++t) {
      s16x8 a = *reinterpret_cast<const s16x8*>(&s_w1[(t * 16 + c) * 136 + kt * 32 + g * 8]);
      #pragma unroll
      for (int mt = 0; mt < 2; ++mt)
        acc[t][mt] = __builtin_amdgcn_mfma_f32_16x16x32_bf16(a, bfr[mt][kt], acc[t][mt], 0, 0, 0);
    }

  #pragma unroll
  for (int t = 0; t < 8; ++t)
    #pragma unroll
    for (int mt = 0; mt < 2; ++mt) {
      long row = base + mt * 16 + c;
      if (row < NN) {
        s16x4 p;
        #pragma unroll
        for (int r = 0; r < 4; ++r) {
          float x = acc[t][mt][r] + s_b1[t * 16 + g * 4 + r];
          p[r] = f2bf(silu(x));
        }
        *reinterpret_cast<s16x4*>(&u_out[row * HID + t * 16 + g * 4]) = p;
      }
    }
}

// ---------------------------------------------------------------- kernel 2b
// out[m][hid] = u . uw2 + ub2   (16x16x16, A from bf16 u in ws)
__global__ __launch_bounds__(256, 2) void k_update2(
    const short* __restrict__ u, const float* __restrict__ uw2,
    const float* __restrict__ ub2, float* __restrict__ out)
{
  __shared__ __align__(16) short s_w2[128 * 136];   // uw2T[h][k]
  __shared__ float s_b2[128];
  const int tid = threadIdx.x;
  for (int i = tid; i < 128 * 128; i += 256) {      // uw2 given [k][h]
    int k = i >> 7, h = i & 127;
    s_w2[h * 136 + k] = f2bf(uw2[i]);
  }
  if (tid < 128) s_b2[tid] = ub2[tid];
  __syncthreads();

  const int wave = tid >> 6, lane = tid & 63;
  const int c = lane & 15, g = lane >> 4;
  const long base = (long)(blockIdx.x * 4 + wave) * 32;
  if (base >= NN) return;

  s16x4 afr[2][8];
  #pragma unroll
  for (int mt = 0; mt < 2; ++mt)
    #pragma unroll
    for (int kt = 0; kt < 8; ++kt) {
      long row = base + mt * 16 + c; if (row > NN - 1) row = NN - 1;
      afr[mt][kt] = *reinterpret_cast<const s16x4*>(&u[row * HID + kt * 16 + g * 4]);
    }

  f32x4 acc[8][2];
  #pragma unroll
  for (int ct = 0; ct < 8; ++ct)
    #pragma unroll
    for (int mt = 0; mt < 2; ++mt)
      acc[ct][mt] = f32x4{0.f, 0.f, 0.f, 0.f};
  #pragma unroll
  for (int ct = 0; ct < 8; ++ct)
    #pragma unroll
    for (int kt = 0; kt < 8; ++kt) {
      s16x4 b2 = *reinterpret_cast<const s16x4*>(&s_w2[(ct * 16 + c) * 136 + kt * 16 + g * 4]);
      #pragma unroll
      for (int mt = 0; mt < 2; ++mt)
        acc[ct][mt] = __builtin_amdgcn_mfma_f32_16x16x16bf16_1k(afr[mt][kt], b2, acc[ct][mt], 0, 0, 0);
    }

  #pragma unroll
  for (int ct = 0; ct < 8; ++ct) {
    const float bias = s_b2[ct * 16 + c];
    #pragma unroll
    for (int mt = 0; mt < 2; ++mt)
      #pragma unroll
      for (int r = 0; r < 4; ++r) {
        long row = base + mt * 16 + g * 4 + r;
        if (row < NN) out[row * HID + ct * 16 + c] = acc[ct][mt][r] + bias;
      }
  }
}

// ---------------------------------------------------------------- launch
extern "C" void kernel_launch(void* const* d_in, const int* in_sizes, int n_in,
                              void* d_out, int out_size, void* d_ws, size_t ws_size,
                              hipStream_t stream) {
  const float* node_repr = (const float*)d_in[0];
  const float* nbr_fea   = (const float*)d_in[1];
  const int*   nbr_idx   = (const int*)d_in[2];
  const float* fw1 = (const float*)d_in[3];
  const float* fb1 = (const float*)d_in[4];
  const float* fw2 = (const float*)d_in[5];
  const float* fb2 = (const float*)d_in[6];
  const float* uw1 = (const float*)d_in[7];
  const float* ub1 = (const float*)d_in[8];
  const float* uw2 = (const float*)d_in[9];
  const float* ub2 = (const float*)d_in[10];
  float* outp = (float*)d_out;
  short* ws16 = (short*)d_ws;   // 12.8 MB: node_bf16 (k0,k1) then u (k2a,k2b)

  k_cvt_node<<<(NN * HID / 4 + 255) / 256, 256, 0, stream>>>(node_repr, ws16);
  // k1: 512 blocks x 512 thr, 2 blocks/CU (LDS 70KB), persistent
  k_filter_message<<<512, 512, 0, stream>>>(ws16, nbr_fea, nbr_idx,
                                            fw1, fb1, fw2, fb2, outp);
  const int rowblocks = (NN + 31) / 32;        // 1563
  const int grid2 = (rowblocks + 3) / 4;       // 391
  k_update1<<<grid2, 256, 0, stream>>>(outp, uw1, ub1, ws16);  // u overwrites node_bf16
  k_update2<<<grid2, 256, 0, stream>>>(ws16, uw2, ub2, outp);
}

// Round 9
// 465.946 us; speedup vs baseline: 1.7650x; 1.7650x over previous
//
#include <hip/hip_runtime.h>

// InteractionBlock: N=50000 nodes, M=32 nbrs, HID=128, FILT=128, NBR=64
//  k0 : node_repr f32 -> bf16 table in d_ws
//  k1 : per-node fused filter MLP (bf16 MFMA) + filter-weighted neighbor sum -> message (d_out)
//  k2a: u = silu(msg@uw1+ub1) -> bf16 u in d_ws (reuses k0 region)
//  k2b: out = u@uw2+ub2 -> d_out
//
// R8 -> R9: BUGFIX. R8's filter tile was declared with stride 72 (copied from
// R7's 64-hid half tile) but written/read with full 128-hid rows (cols up to
// 127) -> every row overflowed into the next. Stride now 136 shorts (272B:
// 16B-multiple so ds_read_b128 stays aligned). Structure otherwise identical:
//  * BLOCK-GATHER: lane (r=l>>3, k=l&7) reads row idx_r, 16B chunk k ->
//    one dwordx4 instruction covers 8 rows x 128B fully-used lines.
//    8 gather instr/node, zero over-fetch, 16B/lane payload.
//    (two-sided gather law: >=128B footprint per row per instruction (R6)
//     AND fat per-lane payload (R7))
//  * all 8 gathers issued BEFORE GEMM1 -> ~600cy MFMA cover
//  * filters relayout via per-wave bf16 LDS tile [16][136]; m-sum via
//    3 shfl_xor rounds over r; coalesced 256B msg store by r==0 lanes
//
// MFMA layout conventions (gfx950, 16x16 family, verified m89/m91):
//   A frag (16x16x32): row = lane&15, k = (lane>>4)*8 + j  (short8)
//   A/B frag (16x16x16bf16_1k): row/col = lane&15, k = (lane>>4)*4 + j (short4)
//   C/D: col = lane&15, row = (lane>>4)*4 + reg
// Transposed GEMM2 (A=w2 frag, B=P): lane holds filter[m=c][hid=16ct+4g+r].

#define NN 50000
#define MM 32
#define HID 128
#define NBR 64

typedef __attribute__((ext_vector_type(4))) float f32x4;
typedef __attribute__((ext_vector_type(8))) short s16x8;
typedef __attribute__((ext_vector_type(4))) short s16x4;

__device__ __forceinline__ short f2bf(float x) {
  unsigned u = __builtin_bit_cast(unsigned, x);
  unsigned r = (u + 0x7FFFu + ((u >> 16) & 1u)) >> 16;
  return (short)r;
}

__device__ __forceinline__ float bf2f(short b) {
  return __builtin_bit_cast(float, (unsigned)(unsigned short)b << 16);
}

__device__ __forceinline__ float silu(float x) {
  return x / (1.0f + __expf(-x));
}

// ---------------------------------------------------------------- kernel 0
__global__ __launch_bounds__(256) void k_cvt_node(
    const float* __restrict__ in, short* __restrict__ out)
{
  int i = blockIdx.x * 256 + threadIdx.x;            // float4 index
  if (i < NN * HID / 4) {
    f32x4 v = *(reinterpret_cast<const f32x4*>(in) + i);
    s16x4 o;
    #pragma unroll
    for (int r = 0; r < 4; ++r) o[r] = f2bf(v[r]);
    reinterpret_cast<s16x4*>(out)[i] = o;
  }
}

// ---------------------------------------------------------------- kernel 1
__global__ __launch_bounds__(256, 2) void k_filter_message(
    const short* __restrict__ node_bf, const float* __restrict__ nbr_fea,
    const int* __restrict__ nbr_idx, const float* __restrict__ fw1,
    const float* __restrict__ fb1, const float* __restrict__ fw2,
    const float* __restrict__ fb2, float* __restrict__ msg_out)
{
  __shared__ __align__(16) short s_w1[128 * 72];      // 18.4 KB  fw1T[f][k]
  __shared__ __align__(16) short s_w2[128 * 136];     // 34.8 KB  fw2T[h][k]
  __shared__ float s_b1[128];
  __shared__ __align__(16) float s_b2[128];
  __shared__ __align__(16) short s_ft[4][16 * 136];   // 17.4 KB per-wave filter tile [16m][128hid+8pad]
  // total 71.7 KB -> 2 blocks/CU

  const int tid = threadIdx.x;
  for (int i = tid; i < 64 * 128; i += 256) {      // fw1 given [k<64][f<128]
    int k = i >> 7, f = i & 127;
    s_w1[f * 72 + k] = f2bf(fw1[i]);
  }
  for (int i = tid; i < 128 * 128; i += 256) {     // fw2 given [k<128][h<128]
    int k = i >> 7, h = i & 127;
    s_w2[h * 136 + k] = f2bf(fw2[i]);
  }
  if (tid < 128) { s_b1[tid] = fb1[tid]; s_b2[tid] = fb2[tid]; }
  __syncthreads();

  const int wave = tid >> 6, lane = tid & 63;
  const int c = lane & 15, g = lane >> 4;     // MFMA fragment coords
  const int r = lane >> 3, k = lane & 7;      // block-gather coords
  short* __restrict__ ft = s_ft[wave];        // wave-private [16 rows][136]
  const int gw = blockIdx.x * 4 + wave;
  const int STRIDE = 512 * 4;                 // 2048 waves

  // prologue: this node's gather row indices, vector form (rows mt*16+8i+r)
  int vidx[2][2];
  #pragma unroll
  for (int mt = 0; mt < 2; ++mt)
    #pragma unroll
    for (int i = 0; i < 2; ++i)
      vidx[mt][i] = nbr_idx[(size_t)gw * MM + mt * 16 + 8 * i + r];

  for (int n = gw; n < NN; n += STRIDE) {
    // 1: issue all 8 block-gather loads NOW (consumed after GEMM2 phases)
    //    lane (r,k): row vidx[mt][i], bf16 chunk hid = 64h + 8k .. +7
    s16x8 gr[2][2][2];   // [mt][i][h]
    #pragma unroll
    for (int mt = 0; mt < 2; ++mt)
      #pragma unroll
      for (int i = 0; i < 2; ++i) {
        const short* rp = node_bf + (size_t)vidx[mt][i] * HID + 8 * k;
        gr[mt][i][0] = *reinterpret_cast<const s16x8*>(rp);
        gr[mt][i][1] = *reinterpret_cast<const s16x8*>(rp + 64);
      }

    // 2: stream nbr_fea (NT) -> B1 frags
    const float* nf = nbr_fea + (size_t)n * (MM * NBR);
    s16x8 b1[2][2];
    #pragma unroll
    for (int mt = 0; mt < 2; ++mt)
      #pragma unroll
      for (int kt = 0; kt < 2; ++kt) {
        const f32x4* src = reinterpret_cast<const f32x4*>(
            nf + (mt * 16 + c) * NBR + kt * 32 + g * 8);
        f32x4 lo = __builtin_nontemporal_load(src);
        f32x4 hi = __builtin_nontemporal_load(src + 1);
        s16x8 v;
        v[0] = f2bf(lo[0]); v[1] = f2bf(lo[1]); v[2] = f2bf(lo[2]); v[3] = f2bf(lo[3]);
        v[4] = f2bf(hi[0]); v[5] = f2bf(hi[1]); v[6] = f2bf(hi[2]); v[7] = f2bf(hi[3]);
        b1[mt][kt] = v;
      }

    // 3: prefetch NEXT node's gather indices
    {
      int n2 = n + STRIDE;
      int np = (n2 < NN) ? n2 : n;
      #pragma unroll
      for (int mt = 0; mt < 2; ++mt)
        #pragma unroll
        for (int i = 0; i < 2; ++i)
          vidx[mt][i] = nbr_idx[(size_t)np * MM + mt * 16 + 8 * i + r];
    }

    // 4: GEMM1 (transposed): h^T = fw1T . nbr^T; bias+silu -> P frags
    s16x4 P[8][2];
    #pragma unroll
    for (int t = 0; t < 8; ++t) {
      f32x4 a0 = f32x4{0.f, 0.f, 0.f, 0.f};
      f32x4 a1 = f32x4{0.f, 0.f, 0.f, 0.f};
      #pragma unroll
      for (int kt = 0; kt < 2; ++kt) {
        s16x8 w1f = *reinterpret_cast<const s16x8*>(&s_w1[(t * 16 + c) * 72 + kt * 32 + g * 8]);
        a0 = __builtin_amdgcn_mfma_f32_16x16x32_bf16(w1f, b1[0][kt], a0, 0, 0, 0);
        a1 = __builtin_amdgcn_mfma_f32_16x16x32_bf16(w1f, b1[1][kt], a1, 0, 0, 0);
      }
      s16x4 p0, p1;
      #pragma unroll
      for (int q = 0; q < 4; ++q) {
        float bias = s_b1[t * 16 + g * 4 + q];
        p0[q] = f2bf(silu(a0[q] + bias));
        p1[q] = f2bf(silu(a1[q] + bias));
      }
      P[t][0] = p0;
      P[t][1] = p1;
    }

    // 5/6: per mt-half: GEMM2 (transposed) -> bf16 tile -> block-gather FMA
    float part0[8], part1[8];   // partial msg, hid = 64h + 8k + j
    #pragma unroll
    for (int j = 0; j < 8; ++j) { part0[j] = 0.f; part1[j] = 0.f; }

    #pragma unroll
    for (int mt = 0; mt < 2; ++mt) {
      // filters for rows m = mt*16 + c -> tile row c (full 128 hid, stride 136)
      #pragma unroll
      for (int ct = 0; ct < 8; ++ct) {
        f32x4 t = f32x4{0.f, 0.f, 0.f, 0.f};
        #pragma unroll
        for (int kt = 0; kt < 8; ++kt) {
          s16x4 w2f = *reinterpret_cast<const s16x4*>(&s_w2[(ct * 16 + c) * 136 + kt * 16 + g * 4]);
          t = __builtin_amdgcn_mfma_f32_16x16x16bf16_1k(w2f, P[kt][mt], t, 0, 0, 0);
        }
        f32x4 fb = *reinterpret_cast<const f32x4*>(&s_b2[ct * 16 + 4 * g]);
        s16x4 pk;
        #pragma unroll
        for (int q = 0; q < 4; ++q) pk[q] = f2bf(t[q] + fb[q]);
        *reinterpret_cast<s16x4*>(&ft[c * 136 + ct * 16 + 4 * g]) = pk;
      }
      // block-gather FMA: lane (r,k) handles tile rows 8i+r, chunk k
      #pragma unroll
      for (int i = 0; i < 2; ++i) {
        s16x8 f0 = *reinterpret_cast<const s16x8*>(&ft[(8 * i + r) * 136 + 8 * k]);
        s16x8 f1 = *reinterpret_cast<const s16x8*>(&ft[(8 * i + r) * 136 + 64 + 8 * k]);
        #pragma unroll
        for (int j = 0; j < 8; ++j) {
          part0[j] += bf2f(f0[j]) * bf2f(gr[mt][i][0][j]);
          part1[j] += bf2f(f1[j]) * bf2f(gr[mt][i][1][j]);
        }
      }
    }

    // 7: reduce over r (stride-8 lanes) and store (lanes r==0, coalesced 256B)
    #pragma unroll
    for (int j = 0; j < 8; ++j) {
      part0[j] += __shfl_xor(part0[j], 8);
      part0[j] += __shfl_xor(part0[j], 16);
      part0[j] += __shfl_xor(part0[j], 32);
      part1[j] += __shfl_xor(part1[j], 8);
      part1[j] += __shfl_xor(part1[j], 16);
      part1[j] += __shfl_xor(part1[j], 32);
    }
    if (r == 0) {
      float* mp = msg_out + (size_t)n * HID + 8 * k;
      *reinterpret_cast<f32x4*>(mp)      = f32x4{part0[0], part0[1], part0[2], part0[3]};
      *reinterpret_cast<f32x4*>(mp + 4)  = f32x4{part0[4], part0[5], part0[6], part0[7]};
      *reinterpret_cast<f32x4*>(mp + 64) = f32x4{part1[0], part1[1], part1[2], part1[3]};
      *reinterpret_cast<f32x4*>(mp + 68) = f32x4{part1[4], part1[5], part1[6], part1[7]};
    }
  }
}

// ---------------------------------------------------------------- kernel 2a
// u^T = silu(uw1^T . msg^T + ub1) -> bf16 u[row][128] in ws
__global__ __launch_bounds__(256, 2) void k_update1(
    const float* __restrict__ msg, const float* __restrict__ uw1,
    const float* __restrict__ ub1, short* __restrict__ u_out)
{
  __shared__ __align__(16) short s_w1[128 * 136];   // uw1T[f][k], stride 136
  __shared__ float s_b1[128];
  const int tid = threadIdx.x;
  for (int i = tid; i < 128 * 128; i += 256) {      // uw1 given [k][f]
    int k = i >> 7, f = i & 127;
    s_w1[f * 136 + k] = f2bf(uw1[i]);
  }
  if (tid < 128) s_b1[tid] = ub1[tid];
  __syncthreads();

  const int wave = tid >> 6, lane = tid & 63;
  const int c = lane & 15, g = lane >> 4;
  const long base = (long)(blockIdx.x * 4 + wave) * 32;
  if (base >= NN) return;

  s16x8 bfr[2][4];
  #pragma unroll
  for (int mt = 0; mt < 2; ++mt)
    #pragma unroll
    for (int kt = 0; kt < 4; ++kt) {
      long row = base + mt * 16 + c; if (row > NN - 1) row = NN - 1;
      const float* src = msg + row * HID + kt * 32 + g * 8;
      float4 lo = *reinterpret_cast<const float4*>(src);
      float4 hi = *reinterpret_cast<const float4*>(src + 4);
      s16x8 v;
      v[0] = f2bf(lo.x); v[1] = f2bf(lo.y); v[2] = f2bf(lo.z); v[3] = f2bf(lo.w);
      v[4] = f2bf(hi.x); v[5] = f2bf(hi.y); v[6] = f2bf(hi.z); v[7] = f2bf(hi.w);
      bfr[mt][kt] = v;
    }

  f32x4 acc[8][2];
  #pragma unroll
  for (int t = 0; t < 8; ++t)
    #pragma unroll
    for (int mt = 0; mt < 2; ++mt)
      acc[t][mt] = f32x4{0.f, 0.f, 0.f, 0.f};
  #pragma unroll
  for (int kt = 0; kt < 4; ++kt)
    #pragma unroll
    for (int t = 0; t < 8; ++t) {
      s16x8 a = *reinterpret_cast<const s16x8*>(&s_w1[(t * 16 + c) * 136 + kt * 32 + g * 8]);
      #pragma unroll
      for (int mt = 0; mt < 2; ++mt)
        acc[t][mt] = __builtin_amdgcn_mfma_f32_16x16x32_bf16(a, bfr[mt][kt], acc[t][mt], 0, 0, 0);
    }

  #pragma unroll
  for (int t = 0; t < 8; ++t)
    #pragma unroll
    for (int mt = 0; mt < 2; ++mt) {
      long row = base + mt * 16 + c;
      if (row < NN) {
        s16x4 p;
        #pragma unroll
        for (int q = 0; q < 4; ++q) {
          float x = acc[t][mt][q] + s_b1[t * 16 + g * 4 + q];
          p[q] = f2bf(silu(x));
        }
        *reinterpret_cast<s16x4*>(&u_out[row * HID + t * 16 + g * 4]) = p;
      }
    }
}

// ---------------------------------------------------------------- kernel 2b
// out[m][hid] = u . uw2 + ub2   (16x16x16, A from bf16 u in ws)
__global__ __launch_bounds__(256, 2) void k_update2(
    const short* __restrict__ u, const float* __restrict__ uw2,
    const float* __restrict__ ub2, float* __restrict__ out)
{
  __shared__ __align__(16) short s_w2[128 * 136];   // uw2T[h][k]
  __shared__ float s_b2[128];
  const int tid = threadIdx.x;
  for (int i = tid; i < 128 * 128; i += 256) {      // uw2 given [k][h]
    int k = i >> 7, h = i & 127;
    s_w2[h * 136 + k] = f2bf(uw2[i]);
  }
  if (tid < 128) s_b2[tid] = ub2[tid];
  __syncthreads();

  const int wave = tid >> 6, lane = tid & 63;
  const int c = lane & 15, g = lane >> 4;
  const long base = (long)(blockIdx.x * 4 + wave) * 32;
  if (base >= NN) return;

  s16x4 afr[2][8];
  #pragma unroll
  for (int mt = 0; mt < 2; ++mt)
    #pragma unroll
    for (int kt = 0; kt < 8; ++kt) {
      long row = base + mt * 16 + c; if (row > NN - 1) row = NN - 1;
      afr[mt][kt] = *reinterpret_cast<const s16x4*>(&u[row * HID + kt * 16 + g * 4]);
    }

  f32x4 acc[8][2];
  #pragma unroll
  for (int ct = 0; ct < 8; ++ct)
    #pragma unroll
    for (int mt = 0; mt < 2; ++mt)
      acc[ct][mt] = f32x4{0.f, 0.f, 0.f, 0.f};
  #pragma unroll
  for (int ct = 0; ct < 8; ++ct)
    #pragma unroll
    for (int kt = 0; kt < 8; ++kt) {
      s16x4 b2 = *reinterpret_cast<const s16x4*>(&s_w2[(ct * 16 + c) * 136 + kt * 16 + g * 4]);
      #pragma unroll
      for (int mt = 0; mt < 2; ++mt)
        acc[ct][mt] = __builtin_amdgcn_mfma_f32_16x16x16bf16_1k(afr[mt][kt], b2, acc[ct][mt], 0, 0, 0);
    }

  #pragma unroll
  for (int ct = 0; ct < 8; ++ct) {
    const float bias = s_b2[ct * 16 + c];
    #pragma unroll
    for (int mt = 0; mt < 2; ++mt)
      #pragma unroll
      for (int q = 0; q < 4; ++q) {
        long row = base + mt * 16 + g * 4 + q;
        if (row < NN) out[row * HID + ct * 16 + c] = acc[ct][mt][q] + bias;
      }
  }
}

// ---------------------------------------------------------------- launch
extern "C" void kernel_launch(void* const* d_in, const int* in_sizes, int n_in,
                              void* d_out, int out_size, void* d_ws, size_t ws_size,
                              hipStream_t stream) {
  const float* node_repr = (const float*)d_in[0];
  const float* nbr_fea   = (const float*)d_in[1];
  const int*   nbr_idx   = (const int*)d_in[2];
  const float* fw1 = (const float*)d_in[3];
  const float* fb1 = (const float*)d_in[4];
  const float* fw2 = (const float*)d_in[5];
  const float* fb2 = (const float*)d_in[6];
  const float* uw1 = (const float*)d_in[7];
  const float* ub1 = (const float*)d_in[8];
  const float* uw2 = (const float*)d_in[9];
  const float* ub2 = (const float*)d_in[10];
  float* outp = (float*)d_out;
  short* ws16 = (short*)d_ws;   // 12.8 MB: node_bf16 (k0,k1) then u (k2a,k2b)

  k_cvt_node<<<(NN * HID / 4 + 255) / 256, 256, 0, stream>>>(node_repr, ws16);
  // k1: 512 blocks x 256 thr, 2 blocks/CU (LDS 71.7KB), persistent
  k_filter_message<<<512, 256, 0, stream>>>(ws16, nbr_fea, nbr_idx,
                                            fw1, fb1, fw2, fb2, outp);
  const int rowblocks = (NN + 31) / 32;        // 1563
  const int grid2 = (rowblocks + 3) / 4;       // 391
  k_update1<<<grid2, 256, 0, stream>>>(outp, uw1, ub1, ws16);  // u overwrites node_bf16
  k_update2<<<grid2, 256, 0, stream>>>(ws16, uw2, ub2, outp);
}